// Round 12
// baseline (18241.194 us; speedup 1.0000x reference)
//
#include <hip/hip_runtime.h>
#include <hip/hip_bf16.h>
#include <math.h>

#define DEV __device__ __forceinline__
typedef unsigned int u32;
typedef unsigned short u16;

constexpr int NNODES = 16384;
constexpr int NEDGE  = 262144;
constexpr int NEL    = NEDGE + NNODES;
constexpr int FIN    = 256;
constexpr int C1     = 384;
constexpr int DM     = 192;
constexpr int BZ     = 128;
constexpr int NPG_   = 128;
constexpr int LL     = 4;
constexpr int PP     = 32;
constexpr int SM     = 33;
constexpr int DFF_   = 512;

// packed-weight layout (uint4 units, [K/8][N]) per layer
constexpr int PL4     = 52224;
constexpr int OFF4_QKV = 0;        // [24][576]
constexpr int OFF4_SAO = 13824;    // [24][192]
constexpr int OFF4_CAQ = 18432;
constexpr int OFF4_CAO = 23040;
constexpr int OFF4_FF1 = 27648;    // [24][512]
constexpr int OFF4_FF2 = 39936;    // [64][192]

// ---- workspace layout (float units) ----
constexpr size_t O_KVK = 0;                       // CA K bf16 [l][node][192] (overlaps dead XP1)
constexpr size_t O_VT  = 6291456;                 // CA V^T bf16 [l][dim][node] (overlaps dead H)
constexpr size_t O_XP1 = 0;
constexpr size_t O_H   = 6291456;
constexpr size_t O_XP2 = 12582912;                // also hidG post-decode
constexpr size_t O_MEM = 15728640;
constexpr size_t O_WP  = 20545536;                // packed weights
constexpr size_t O_PE  = 21424128;
constexpr size_t O_AL1S= O_PE + 6336;
constexpr size_t O_AL1D= O_AL1S + 65536;
constexpr size_t O_AL2S= O_AL1D + 65536;
constexpr size_t O_AL2D= O_AL2S + 16384;
constexpr size_t O_CNT = O_AL2D + 16384;
constexpr size_t O_BASE= O_CNT + 16384;
constexpr size_t O_FILL= O_BASE + 16384;
constexpr size_t O_CSRC= O_FILL + 16384;
constexpr size_t O_LASTS=O_CSRC + 278528;         // 4096*192 fp32
constexpr size_t O_VSAT= O_LASTS + 786432;        // SA V cache u16: 128*4*192*34

DEV float gelu_f(float v) { return 0.5f*v*(1.0f + erff(v*0.7071067811865475f)); }
DEV float bflo(u32 w) { return __uint_as_float(w << 16); }
DEV float bfhi(u32 w) { return __uint_as_float(w & 0xffff0000u); }
DEV float bfu(u16 u)  { return __uint_as_float(((u32)u) << 16); }
DEV u16 bf16u(float a) {
  __hip_bfloat16 h = __float2bfloat16(a);
  return *reinterpret_cast<u16*>(&h);
}
DEV u32 pk2(float a, float b) {
  return (u32)bf16u(a) | ((u32)bf16u(b) << 16);
}
DEV void fma8(float& a, uint4 w, float4 xa, float4 xb) {
  a = fmaf(bflo(w.x), xa.x, a); a = fmaf(bfhi(w.x), xa.y, a);
  a = fmaf(bflo(w.y), xa.z, a); a = fmaf(bfhi(w.y), xa.w, a);
  a = fmaf(bflo(w.z), xb.x, a); a = fmaf(bfhi(w.z), xb.y, a);
  a = fmaf(bflo(w.w), xb.z, a); a = fmaf(bfhi(w.w), xb.w, a);
}
// shared-weight dual-batch dot: load w once, FMA into both batches' accumulators
template<int NU4, int STRIDE>
DEV void dotcol2(const uint4* __restrict__ col, const float* __restrict__ xa_,
                 const float* __restrict__ xb_, float& ra, float& rb) {
  const float4* xA = (const float4*)xa_;
  const float4* xB = (const float4*)xb_;
  float a0 = 0, a1 = 0, b0 = 0, b1 = 0;
  #pragma unroll
  for (int q = 0; q < NU4; ++q) {
    uint4 w = col[(size_t)q*STRIDE];
    float4 pa = xA[2*q], qa = xA[2*q+1];
    float4 pb = xB[2*q], qb = xB[2*q+1];
    if (q & 1) { fma8(a1, w, pa, qa); fma8(b1, w, pb, qb); }
    else       { fma8(a0, w, pa, qa); fma8(b0, w, pb, qb); }
  }
  ra = a0 + a1; rb = b0 + b1;
}
// small prefetch buffer (12 VGPRs)
template<int N> struct WB { uint4 w[N]; };
template<int N, int STRIDE>
DEV void wissue(WB<N>& r, const uint4* __restrict__ col) {
  #pragma unroll
  for (int q = 0; q < N; ++q) r.w[q] = col[(size_t)q*STRIDE];
}
template<int N>
DEV float wuse(const WB<N>& r, const float* __restrict__ xv) {
  const float4* x4 = (const float4*)xv;
  float a0 = 0, a1 = 0;
  #pragma unroll
  for (int q = 0; q < N; ++q) {
    float4 xa = x4[2*q], xb = x4[2*q+1];
    if (q & 1) fma8(a1, r.w[q], xa, xb);
    else       fma8(a0, r.w[q], xa, xb);
  }
  return a0 + a1;
}

// ---------------- misc ----------------
__global__ void zero_kernel(float* adj, int* cnt, int* fill) {
  int i = blockIdx.x*256 + threadIdx.x;
  if (i < BZ*SM*SM) adj[i] = 0.f;
  if (i < NNODES) { cnt[i] = 0; fill[i] = 0; }
}

__global__ void pe_kernel(float* pe) {
  int idx = blockIdx.x*256 + threadIdx.x;
  if (idx >= SM*DM) return;
  int p = idx / DM, d = idx % DM;
  int i2 = d >> 1;
  float div = __expf((float)(2*i2) * (-9.210340371976184f / (float)DM));
  float a = (float)p * div;
  pe[idx] = (d & 1) ? cosf(a) : sinf(a);
}

__global__ void pack_kernel(const float* __restrict__ W, uint4* __restrict__ P, int N, int K) {
  int idx = blockIdx.x*256 + threadIdx.x;
  if (idx >= N*(K>>3)) return;
  int o = idx % N, kq = idx / N;
  const float* r = W + (size_t)o*K + 8*kq;
  uint4 u;
  u.x = pk2(r[0], r[1]); u.y = pk2(r[2], r[3]);
  u.z = pk2(r[4], r[5]); u.w = pk2(r[6], r[7]);
  P[idx] = u;
}

// ---------------- generic fp32 GEMM: C[M,N] = A[M,K] @ W[N,K]^T (+bias, opt gelu) --------
template<int BMODE, bool BF16OUT, bool GELU = false>
__global__ __launch_bounds__(256) void gemm_nt(const float* __restrict__ A,
    const float* __restrict__ W, const float* __restrict__ bias,
    float* __restrict__ Cf, __hip_bfloat16* __restrict__ Cb, int M, int N, int K)
{
  __shared__ float As[16][68];
  __shared__ float Ws[16][68];
  const int bm = blockIdx.y*64, bn = blockIdx.x*64;
  const int t = threadIdx.x, tx = t & 15, ty = t >> 4;
  float acc[4][4] = {};
  for (int k0 = 0; k0 < K; k0 += 16) {
    #pragma unroll
    for (int i = 0; i < 4; ++i) {
      int idx = t + i*256, kk = idx & 15, m = idx >> 4;
      As[kk][m] = A[(size_t)(bm+m)*K + k0+kk];
      Ws[kk][m] = W[(size_t)(bn+m)*K + k0+kk];
    }
    __syncthreads();
    #pragma unroll
    for (int kk = 0; kk < 16; ++kk) {
      const float4 a4 = *(const float4*)&As[kk][ty*4];
      const float4 b4 = *(const float4*)&Ws[kk][tx*4];
      const float av[4] = {a4.x,a4.y,a4.z,a4.w};
      const float bv[4] = {b4.x,b4.y,b4.z,b4.w};
      #pragma unroll
      for (int i = 0; i < 4; ++i)
        #pragma unroll
        for (int j = 0; j < 4; ++j)
          acc[i][j] = fmaf(av[i], bv[j], acc[i][j]);
    }
    __syncthreads();
  }
  #pragma unroll
  for (int i = 0; i < 4; ++i) {
    const int m = bm + ty*4 + i;
    #pragma unroll
    for (int j = 0; j < 4; ++j) {
      const int n = bn + tx*4 + j;
      float v = acc[i][j];
      if (BMODE == 1) v += bias[n];
      if (BMODE == 2) v += bias[m];
      if (GELU) v = gelu_f(v);
      if (BF16OUT) Cb[(size_t)m*N + n] = __float2bfloat16(v);
      else         Cf[(size_t)m*N + n] = v;
    }
  }
}

// ---------------- GAT helpers ----------------
template<int HEADS, int CH>
__global__ void al_kernel(const float* __restrict__ xp, const float* __restrict__ asrc,
                          const float* __restrict__ adst, float* als, float* ald) {
  int idx = blockIdx.x*256 + threadIdx.x;
  if (idx >= NNODES*HEADS) return;
  int n = idx / HEADS, h = idx % HEADS;
  const float* row = xp + (size_t)n*(HEADS*CH) + h*CH;
  float s = 0, d = 0;
  for (int c = 0; c < CH; ++c) { float v = row[c]; s = fmaf(v, asrc[h*CH+c], s); d = fmaf(v, adst[h*CH+c], d); }
  als[idx] = s; ald[idx] = d;
}

__global__ void count_kernel(const int* __restrict__ dst, int* cnt) {
  int e = blockIdx.x*256 + threadIdx.x;
  if (e < NEDGE) atomicAdd(&cnt[dst[e]], 1);
}

__global__ __launch_bounds__(1024) void scan_kernel(const int* __restrict__ cnt, int* base) {
  __shared__ int tot[1024];
  int t = threadIdx.x;
  int local[16]; int s = 0;
  #pragma unroll
  for (int i = 0; i < 16; ++i) { int v = cnt[t*16+i] + 1; local[i] = s; s += v; }
  tot[t] = s; __syncthreads();
  if (t == 0) { int r = 0; for (int i = 0; i < 1024; ++i) { int v = tot[i]; tot[i] = r; r += v; } }
  __syncthreads();
  int off = tot[t];
  #pragma unroll
  for (int i = 0; i < 16; ++i) base[t*16+i] = off + local[i];
}

__global__ void scatter_kernel(const int* __restrict__ src, const int* __restrict__ dst,
                               const int* __restrict__ base, int* fill, int* csrc) {
  int e = blockIdx.x*256 + threadIdx.x;
  if (e < NEDGE) {
    int d = dst[e];
    int p = atomicAdd(&fill[d], 1);
    csrc[base[d] + p] = src[e];
  } else if (e < NEL) {
    int n = e - NEDGE;
    int p = atomicAdd(&fill[n], 1);
    csrc[base[n] + p] = n;
  }
}

template<int HEADS, int CH, bool ELU>
__global__ __launch_bounds__(128) void agg_kernel(const float* __restrict__ xp,
    const float* __restrict__ als, const float* __restrict__ ald,
    const int* __restrict__ cnt, const int* __restrict__ base, const int* __restrict__ csrc,
    const float* __restrict__ bias, float* __restrict__ out)
{
  constexpr int CO = HEADS*CH;
  constexpr int MAXD = 128;
  int n = blockIdx.x, t = threadIdx.x;
  int deg = cnt[n] + 1, st = base[n];
  if (deg > MAXD) deg = MAXD;
  __shared__ int   srcs[MAXD];
  __shared__ float ex[MAXD][HEADS];
  __shared__ float den[HEADS];
  for (int j = t; j < deg; j += 128) srcs[j] = csrc[st + j];
  __syncthreads();
  for (int idx = t; idx < deg*HEADS; idx += 128) {
    int j = idx / HEADS, h = idx % HEADS;
    float e = als[srcs[j]*HEADS + h] + ald[n*HEADS + h];
    ex[j][h] = (e > 0.f) ? e : 0.2f*e;
  }
  __syncthreads();
  if (t < HEADS) {
    float m = -1e30f;
    for (int j = 0; j < deg; ++j) m = fmaxf(m, ex[j][t]);
    float s = 0;
    for (int j = 0; j < deg; ++j) { float v = __expf(ex[j][t]-m); ex[j][t] = v; s += v; }
    den[t] = 1.0f/(s + 1e-16f);
  }
  __syncthreads();
  for (int c = t; c < CO; c += 128) {
    int h = c / CH;
    float acc = 0;
    for (int j = 0; j < deg; ++j) acc = fmaf(ex[j][h], xp[(size_t)srcs[j]*CO + c], acc);
    float v = acc*den[h] + bias[c];
    if (ELU) v = (v > 0.f) ? v : (__expf(v) - 1.0f);
    out[(size_t)n*CO + c] = v;
  }
}

// ---------------- post-decode head kernels ----------------
__global__ void adj_kernel(const float* __restrict__ lastsG, float* __restrict__ adj) {
  int b = blockIdx.x, i = blockIdx.y, jj = threadIdx.x;
  if (jj > i) return;
  const float* li = lastsG + ((size_t)b*PP + i)*DM;
  const float* lj = lastsG + ((size_t)b*PP + jj)*DM;
  float a = 0.f;
  for (int d = 0; d < DM; ++d) a = fmaf(lj[d], li[d], a);
  if (jj == 0) {
    adj[((size_t)b*SM + i)*SM + 32] = a;
    adj[((size_t)b*SM + 32)*SM + i] = a;
  } else {
    adj[((size_t)b*SM + jj-1)*SM + i] = a;
    adj[((size_t)b*SM + i)*SM + jj-1] = a;
  }
}

// ---------------- decode: 2 batches per block, shared weight stream ----------------
__global__ __launch_bounds__(1024, 1) void decode_kernel(
    const float* __restrict__ mem, const u16* __restrict__ kvk, const u16* __restrict__ vT,
    const uint4* __restrict__ wp, const float* __restrict__ pe,
    u16* __restrict__ vsaT, const int* __restrict__ tgt_idx,
    const float* __restrict__ saqkvb, const float* __restrict__ saoutb,
    const float* __restrict__ caqkvb, const float* __restrict__ caoutb,
    const float* __restrict__ ff1b, const float* __restrict__ ff2b,
    const float* __restrict__ lng, const float* __restrict__ lnb,
    float* __restrict__ lastsG)
{
  const int t = threadIdx.x;
  const int wv = t >> 6, lane = t & 63;
  const int b0 = blockIdx.x, b1 = blockIdx.x + 64;
  __shared__ u16   ksa16[2*4*33*194];    // SA K caches, per batch, row stride 194 u16
  __shared__ __align__(16) float x2[2][DM];
  __shared__ __align__(16) float qkv2[2][DM];
  __shared__ __align__(16) float attno2[2][DM];
  __shared__ __align__(16) float hid2[2][DFF_];
  __shared__ float prob2[2][33*9 + 7];
  __shared__ float cprob2[2][128*9 + 2];
  __shared__ __align__(16) float psA[2][1152];
  __shared__ float red[16];
  const float scl = 0.2041241452319315f; // 1/sqrt(24)
  const uint4* kvk4 = (const uint4*)kvk;

  // static mappings
  const int qks = t / 576, qcol = t - qks*576;              // QKV split-K2
  const int kF  = t >> 9,  oF   = t & 511;                  // FF1 split-K2
  const int ks4 = (t < 768) ? t/192 : 0;                    // 768-unit phases
  const int o192 = t - ((t < 768) ? (t/192)*192 : 0);
  const int caj = t >> 3, cah = t & 7;                      // CA QK (key,head)
  const int lbb = (t < 384) ? t/192 : 0;                    // 384-unit (bb,col)
  const int lcol = t - ((t < 384) ? (t/192)*192 : 0);
  const int lbg = lbb ? b1 : b0;

  WB<3> rK0, rK1;   // CA-K prefetch, one per batch (24 VGPRs)

  // prologue
  if (t < 384) x2[lbb][lcol] = mem[((size_t)lbg*NPG_ + tgt_idx[lbg])*DM + lcol] + pe[lcol];
  __syncthreads();

  for (int i = 0; i < PP; ++i) {
    for (int l = 0; l < LL; ++l) {
      const uint4* WL = wp + (size_t)l*PL4;
      // P1: SA qkv split-K2, dual batch (1152 units) + CA-K prefetch both batches
      {
        float ra, rb;
        dotcol2<12,576>(WL + OFF4_QKV + qks*12*576 + qcol, x2[0] + 96*qks, x2[1] + 96*qks, ra, rb);
        float bia = qks ? 0.f : saqkvb[l*576 + qcol];
        psA[0][qks*576 + qcol] = ra + bia;
        psA[1][qks*576 + qcol] = rb + bia;
        if (t < 128) {
          int c2 = 448 + t;
          dotcol2<12,576>(WL + OFF4_QKV + 12*576 + c2, x2[0] + 96, x2[1] + 96, ra, rb);
          psA[0][576 + c2] = ra; psA[1][576 + c2] = rb;
        }
      }
      wissue<3,1>(rK0, kvk4 + ((size_t)l*NNODES + b0*NPG_ + caj)*24 + cah*3);
      wissue<3,1>(rK1, kvk4 + ((size_t)l*NNODES + b1*NPG_ + caj)*24 + cah*3);
      __syncthreads();
      // P2: route (1152 units: bb x 576 cols)
      {
        int u = t;
        #pragma unroll
        for (int pass = 0; pass < 2; ++pass) {
          if (pass == 0 || t < 128) {
            int bb = u / 576, col = u - bb*576;
            float a = psA[bb][col] + psA[bb][576 + col];
            int bg = bb ? b1 : b0;
            if (col < 192)      qkv2[bb][col] = a;
            else if (col < 384) ksa16[bb*25608 + (l*33 + i)*194 + (col-192)] = bf16u(a);
            else                vsaT[(((size_t)bg*4 + l)*192 + (col-384))*34 + i] = bf16u(a);
          }
          u = 1024 + t;
        }
      }
      __syncthreads();
      // P3: SA QK^T + softmax + PV fused (wave: bb = wv>>3, head = wv&7)
      {
        int bb = wv >> 3, hh = wv & 7;
        int bg = bb ? b1 : b0;
        float s = -1e30f;
        if (lane <= i) {
          const u32* kr = (const u32*)(ksa16 + bb*25608) + ((size_t)l*33 + lane)*97 + hh*12;
          float a0 = 0, a1 = 0;
          #pragma unroll
          for (int c = 0; c < 12; c += 2) {
            u32 w0 = kr[c], w1 = kr[c+1];
            a0 = fmaf(bflo(w0), qkv2[bb][hh*24 + 2*c],   a0);
            a0 = fmaf(bfhi(w0), qkv2[bb][hh*24 + 2*c+1], a0);
            a1 = fmaf(bflo(w1), qkv2[bb][hh*24 + 2*c+2], a1);
            a1 = fmaf(bfhi(w1), qkv2[bb][hh*24 + 2*c+3], a1);
          }
          s = (a0+a1) * scl;
        }
        float m = s;
        #pragma unroll
        for (int o2 = 32; o2; o2 >>= 1) m = fmaxf(m, __shfl_xor(m, o2, 64));
        float e = (lane <= i) ? __expf(s - m) : 0.f;
        float sm = e;
        #pragma unroll
        for (int o2 = 32; o2; o2 >>= 1) sm += __shfl_xor(sm, o2, 64);
        if (lane <= i) prob2[bb][lane*9 + hh] = e;
        float pinv = 1.0f / sm;
        if (lane < 24) {
          const u16* vr = vsaT + (((size_t)bg*4 + l)*192 + hh*24 + lane)*34;
          float a0 = 0, a1 = 0;
          for (int j = 0; j + 1 <= i; j += 2) {
            a0 = fmaf(prob2[bb][j*9 + hh],     bfu(vr[j]),   a0);
            a1 = fmaf(prob2[bb][(j+1)*9 + hh], bfu(vr[j+1]), a1);
          }
          if (!(i & 1)) a0 = fmaf(prob2[bb][i*9 + hh], bfu(vr[i]), a0);
          attno2[bb][hh*24 + lane] = (a0 + a1) * pinv;
        }
      }
      __syncthreads();
      // P4: SA out split-K4 dual batch (768 units)
      if (t < 768) {
        float ra, rb;
        dotcol2<6,192>(WL + OFF4_SAO + ks4*6*192 + o192, attno2[0] + 48*ks4, attno2[1] + 48*ks4, ra, rb);
        float bia = ks4 ? 0.f : saoutb[l*DM + o192];
        psA[0][ks4*192 + o192] = ra + bia;
        psA[1][ks4*192 + o192] = rb + bia;
      }
      __syncthreads();
      // P5/P6: LN1 (combine+reduce, apply)
      float vres = 0.f;
      {
        if (t < 384) vres = x2[lbb][lcol] + ((psA[lbb][lcol]+psA[lbb][192+lcol]) + (psA[lbb][384+lcol]+psA[lbb][576+lcol]));
        float s = vres, q = vres*vres;
        #pragma unroll
        for (int o = 32; o; o >>= 1) { s += __shfl_down(s, o, 64); q += __shfl_down(q, o, 64); }
        if (lane == 0 && wv < 6) { red[wv] = s; red[8+wv] = q; }
      }
      __syncthreads();
      {
        float S = lbb ? red[3]+red[4]+red[5] : red[0]+red[1]+red[2];
        float Q = lbb ? red[11]+red[12]+red[13] : red[8]+red[9]+red[10];
        float mu = S*(1.f/DM), var = Q*(1.f/DM) - mu*mu;
        float rstd = rsqrtf(var + 1e-5f);
        if (t < 384) x2[lbb][lcol] = (vres-mu)*rstd*lng[(l*3+0)*DM + lcol] + lnb[(l*3+0)*DM + lcol];
      }
      __syncthreads();
      // P7: CA q split-K4 dual batch
      if (t < 768) {
        float ra, rb;
        dotcol2<6,192>(WL + OFF4_CAQ + ks4*6*192 + o192, x2[0] + 48*ks4, x2[1] + 48*ks4, ra, rb);
        float bia = ks4 ? 0.f : caqkvb[l*3*DM + o192];
        psA[0][ks4*192 + o192] = ra + bia;
        psA[1][ks4*192 + o192] = rb + bia;
      }
      __syncthreads();
      // P8: combine CA q
      if (t < 384) qkv2[lbb][lcol] = (psA[lbb][lcol]+psA[lbb][192+lcol]) + (psA[lbb][384+lcol]+psA[lbb][576+lcol]);
      __syncthreads();
      // P9: CA QK^T from prefetched K, both batches (1024 threads = key x head)
      cprob2[0][caj*9 + cah] = scl * wuse<3>(rK0, qkv2[0] + cah*24);
      cprob2[1][caj*9 + cah] = scl * wuse<3>(rK1, qkv2[1] + cah*24);
      __syncthreads();
      // P10: CA softmax + PV fused (wave: bb, head)
      {
        int bb = wv >> 3, hh = wv & 7;
        int bg = bb ? b1 : b0;
        float s0 = cprob2[bb][lane*9 + hh], s1 = cprob2[bb][(lane+64)*9 + hh];
        float m = fmaxf(s0, s1);
        #pragma unroll
        for (int o2 = 32; o2; o2 >>= 1) m = fmaxf(m, __shfl_xor(m, o2, 64));
        float e0 = __expf(s0-m), e1 = __expf(s1-m);
        float sm = e0+e1;
        #pragma unroll
        for (int o2 = 32; o2; o2 >>= 1) sm += __shfl_xor(sm, o2, 64);
        cprob2[bb][lane*9 + hh] = e0; cprob2[bb][(lane+64)*9 + hh] = e1;
        float cinv = 1.0f / sm;
        if (lane < 24) {
          const int d = hh*24 + lane;
          const uint4* v4 = (const uint4*)(vT + ((size_t)l*DM + d)*NNODES + bg*NPG_);
          float a0 = 0, a1 = 0;
          #pragma unroll
          for (int q = 0; q < 16; ++q) {
            uint4 w = v4[q];
            int j0 = q*8;
            a0 = fmaf(cprob2[bb][(j0+0)*9 + hh], bflo(w.x), a0);
            a1 = fmaf(cprob2[bb][(j0+1)*9 + hh], bfhi(w.x), a1);
            a0 = fmaf(cprob2[bb][(j0+2)*9 + hh], bflo(w.y), a0);
            a1 = fmaf(cprob2[bb][(j0+3)*9 + hh], bfhi(w.y), a1);
            a0 = fmaf(cprob2[bb][(j0+4)*9 + hh], bflo(w.z), a0);
            a1 = fmaf(cprob2[bb][(j0+5)*9 + hh], bfhi(w.z), a1);
            a0 = fmaf(cprob2[bb][(j0+6)*9 + hh], bflo(w.w), a0);
            a1 = fmaf(cprob2[bb][(j0+7)*9 + hh], bfhi(w.w), a1);
          }
          attno2[bb][d] = (a0 + a1) * cinv;
        }
      }
      __syncthreads();
      // P11: CA out split-K4 dual batch
      if (t < 768) {
        float ra, rb;
        dotcol2<6,192>(WL + OFF4_CAO + ks4*6*192 + o192, attno2[0] + 48*ks4, attno2[1] + 48*ks4, ra, rb);
        float bia = ks4 ? 0.f : caoutb[l*DM + o192];
        psA[0][ks4*192 + o192] = ra + bia;
        psA[1][ks4*192 + o192] = rb + bia;
      }
      __syncthreads();
      // P12/P13: LN2
      vres = 0.f;
      {
        if (t < 384) vres = x2[lbb][lcol] + ((psA[lbb][lcol]+psA[lbb][192+lcol]) + (psA[lbb][384+lcol]+psA[lbb][576+lcol]));
        float s = vres, q = vres*vres;
        #pragma unroll
        for (int o = 32; o; o >>= 1) { s += __shfl_down(s, o, 64); q += __shfl_down(q, o, 64); }
        if (lane == 0 && wv < 6) { red[wv] = s; red[8+wv] = q; }
      }
      __syncthreads();
      {
        float S = lbb ? red[3]+red[4]+red[5] : red[0]+red[1]+red[2];
        float Q = lbb ? red[11]+red[12]+red[13] : red[8]+red[9]+red[10];
        float mu = S*(1.f/DM), var = Q*(1.f/DM) - mu*mu;
        float rstd = rsqrtf(var + 1e-5f);
        if (t < 384) x2[lbb][lcol] = (vres-mu)*rstd*lng[(l*3+1)*DM + lcol] + lnb[(l*3+1)*DM + lcol];
      }
      __syncthreads();
      // P14: FF1 split-K2 dual batch (1024 units)
      {
        float ra, rb;
        dotcol2<12,512>(WL + OFF4_FF1 + kF*12*512 + oF, x2[0] + 96*kF, x2[1] + 96*kF, ra, rb);
        float bia = kF ? 0.f : ff1b[l*DFF_ + oF];
        psA[0][kF*512 + oF] = ra + bia;
        psA[1][kF*512 + oF] = rb + bia;
      }
      __syncthreads();
      // P15: gelu (1024 units: bb x 512)
      {
        int bb = t >> 9, col = t & 511;
        hid2[bb][col] = gelu_f(psA[bb][col] + psA[bb][512+col]);
      }
      __syncthreads();
      // P16: FF2 split-K4 dual batch (768 units)
      if (t < 768) {
        float ra, rb;
        dotcol2<16,192>(WL + OFF4_FF2 + ks4*16*192 + o192, hid2[0] + 128*ks4, hid2[1] + 128*ks4, ra, rb);
        float bia = ks4 ? 0.f : ff2b[l*DM + o192];
        psA[0][ks4*192 + o192] = ra + bia;
        psA[1][ks4*192 + o192] = rb + bia;
      }
      __syncthreads();
      // P17/P18: LN3
      vres = 0.f;
      {
        if (t < 384) vres = x2[lbb][lcol] + ((psA[lbb][lcol]+psA[lbb][192+lcol]) + (psA[lbb][384+lcol]+psA[lbb][576+lcol]));
        float s = vres, q = vres*vres;
        #pragma unroll
        for (int o = 32; o; o >>= 1) { s += __shfl_down(s, o, 64); q += __shfl_down(q, o, 64); }
        if (lane == 0 && wv < 6) { red[wv] = s; red[8+wv] = q; }
      }
      __syncthreads();
      {
        float S = lbb ? red[3]+red[4]+red[5] : red[0]+red[1]+red[2];
        float Q = lbb ? red[11]+red[12]+red[13] : red[8]+red[9]+red[10];
        float mu = S*(1.f/DM), var = Q*(1.f/DM) - mu*mu;
        float rstd = rsqrtf(var + 1e-5f);
        if (t < 384) x2[lbb][lcol] = (vres-mu)*rstd*lng[(l*3+2)*DM + lcol] + lnb[(l*3+2)*DM + lcol];
      }
      __syncthreads();
    }
    // step-final: store lasts; advance x
    if (t < 384) {
      float xv = x2[lbb][lcol];
      lastsG[((size_t)lbg*PP + i)*DM + lcol] = xv;
      if (i + 1 < PP) x2[lbb][lcol] = xv + pe[(i+1)*DM + lcol];
    }
    __syncthreads();
  }
}

// ---------------- launch ----------------
extern "C" void kernel_launch(void* const* d_in, const int* in_sizes, int n_in,
                              void* d_out, int out_size, void* d_ws, size_t ws_size,
                              hipStream_t stream) {
  (void)in_sizes; (void)n_in; (void)out_size; (void)ws_size;
  const float* x_in    = (const float*)d_in[0];
  const int*   ei      = (const int*)d_in[1];
  const int*   tgt_idx = (const int*)d_in[2];
  const float* gat1_w  = (const float*)d_in[5];
  const float* g1as    = (const float*)d_in[6];
  const float* g1ad    = (const float*)d_in[7];
  const float* g1b     = (const float*)d_in[8];
  const float* gat2_w  = (const float*)d_in[9];
  const float* g2as    = (const float*)d_in[10];
  const float* g2ad    = (const float*)d_in[11];
  const float* g2b     = (const float*)d_in[12];
  const float* saqkvw  = (const float*)d_in[13];
  const float* saqkvb  = (const float*)d_in[14];
  const float* saoutw  = (const float*)d_in[15];
  const float* saoutb  = (const float*)d_in[16];
  const float* caqkvw  = (const float*)d_in[17];
  const float* caqkvb  = (const float*)d_in[18];
  const float* caoutw  = (const float*)d_in[19];
  const float* caoutb  = (const float*)d_in[20];
  const float* ff1w    = (const float*)d_in[21];
  const float* ff1b    = (const float*)d_in[22];
  const float* ff2w    = (const float*)d_in[23];
  const float* ff2b    = (const float*)d_in[24];
  const float* lng     = (const float*)d_in[25];
  const float* lnb     = (const float*)d_in[26];
  const float* h1w     = (const float*)d_in[27];
  const float* h1b     = (const float*)d_in[28];
  const float* h2w     = (const float*)d_in[29];
  const float* h2b     = (const float*)d_in[30];

  float* ws  = (float*)d_ws;
  float* out = (float*)d_out;
  float* adj = out + (size_t)BZ*PP*256;

  const int* src = ei;
  const int* dst = ei + NEDGE;

  int* cnt  = (int*)(ws + O_CNT);
  int* base = (int*)(ws + O_BASE);
  int* fill = (int*)(ws + O_FILL);
  int* csrc = (int*)(ws + O_CSRC);
  float* lastsG = ws + O_LASTS;
  float* hidG   = ws + O_XP2;     // dead post-decode
  u16*   vsaT   = (u16*)(ws + O_VSAT);

  hipLaunchKernelGGL(zero_kernel, dim3(545), dim3(256), 0, stream, adj, cnt, fill);

  // ---- GAT1 ----
  hipLaunchKernelGGL((gemm_nt<0,false>), dim3(C1/64, NNODES/64), dim3(256), 0, stream,
                     x_in, gat1_w, (const float*)nullptr, ws + O_XP1, (__hip_bfloat16*)nullptr,
                     NNODES, C1, FIN);
  hipLaunchKernelGGL((al_kernel<4,96>), dim3(NNODES*4/256), dim3(256), 0, stream,
                     ws+O_XP1, g1as, g1ad, ws+O_AL1S, ws+O_AL1D);
  hipLaunchKernelGGL(count_kernel, dim3(NEDGE/256), dim3(256), 0, stream, dst, cnt);
  hipLaunchKernelGGL(scan_kernel, dim3(1), dim3(1024), 0, stream, cnt, base);
  hipLaunchKernelGGL(scatter_kernel, dim3(NEL/256), dim3(256), 0, stream, src, dst, base, fill, csrc);
  hipLaunchKernelGGL((agg_kernel<4,96,true>), dim3(NNODES), dim3(128), 0, stream,
                     ws+O_XP1, ws+O_AL1S, ws+O_AL1D, cnt, base, csrc, g1b, ws+O_H);

  // ---- GAT2 ----
  hipLaunchKernelGGL((gemm_nt<0,false>), dim3(DM/64, NNODES/64), dim3(256), 0, stream,
                     ws+O_H, gat2_w, (const float*)nullptr, ws+O_XP2, (__hip_bfloat16*)nullptr,
                     NNODES, DM, C1);
  hipLaunchKernelGGL((al_kernel<1,192>), dim3(NNODES/256), dim3(256), 0, stream,
                     ws+O_XP2, g2as, g2ad, ws+O_AL2S, ws+O_AL2D);
  hipLaunchKernelGGL((agg_kernel<1,192,false>), dim3(NNODES), dim3(128), 0, stream,
                     ws+O_XP2, ws+O_AL2S, ws+O_AL2D, cnt, base, csrc, g2b, ws+O_MEM);

  // ---- pack decode weights to bf16 [K/8][N] uint4 ----
  uint4* wp = (uint4*)(ws + O_WP);
  auto PK = [&](const float* Wsrc, int off_u4, int N, int K) {
    hipLaunchKernelGGL(pack_kernel, dim3((N*(K/8)+255)/256), dim3(256), 0, stream,
                       Wsrc, wp + off_u4, N, K);
  };
  for (int l = 0; l < LL; ++l) {
    PK(saqkvw + (size_t)l*110592, l*PL4 + OFF4_QKV, 576, 192);
    PK(saoutw + (size_t)l*36864,  l*PL4 + OFF4_SAO, 192, 192);
    PK(caqkvw + (size_t)l*110592, l*PL4 + OFF4_CAQ, 192, 192);  // first 192 rows = Wq
    PK(caoutw + (size_t)l*36864,  l*PL4 + OFF4_CAO, 192, 192);
    PK(ff1w   + (size_t)l*98304,  l*PL4 + OFF4_FF1, 512, 192);
    PK(ff2w   + (size_t)l*98304,  l*PL4 + OFF4_FF2, 192, 512);
  }

  hipLaunchKernelGGL(pe_kernel, dim3((SM*DM+255)/256), dim3(256), 0, stream, ws+O_PE);

  // ---- CA K (row layout) and V (transposed [dim][node]) hoisted per layer ----
  __hip_bfloat16* kvk = (__hip_bfloat16*)(ws + O_KVK);
  __hip_bfloat16* vTp = (__hip_bfloat16*)(ws + O_VT);
  for (int l = 0; l < LL; ++l) {
    hipLaunchKernelGGL((gemm_nt<1,true>), dim3(DM/64, NNODES/64), dim3(256), 0, stream,
                       ws+O_MEM, caqkvw + (size_t)l*110592 + (size_t)192*192,
                       caqkvb + l*576 + 192, (float*)nullptr,
                       kvk + (size_t)l*NNODES*DM, NNODES, DM, DM);
    hipLaunchKernelGGL((gemm_nt<2,true>), dim3(NNODES/64, DM/64), dim3(256), 0, stream,
                       caqkvw + (size_t)l*110592 + (size_t)2*192*192, ws+O_MEM,
                       caqkvb + l*576 + 384, (float*)nullptr,
                       vTp + (size_t)l*DM*NNODES, DM, NNODES, DM);
  }

  hipLaunchKernelGGL(decode_kernel, dim3(BZ/2), dim3(1024), 0, stream,
                     ws+O_MEM, (const u16*)kvk, (const u16*)vTp, wp, ws+O_PE, vsaT, tgt_idx,
                     saqkvb, saoutb, caqkvb, caoutb, ff1b, ff2b, lng, lnb,
                     lastsG);

  // ---- head (parallel, after decode): feats = gelu(lasts@h1^T)@h2^T ; adj dots ----
  hipLaunchKernelGGL((gemm_nt<1,false,true>), dim3(DM/64, (BZ*PP)/64), dim3(256), 0, stream,
                     lastsG, h1w, h1b, hidG, (__hip_bfloat16*)nullptr,
                     BZ*PP, DM, DM);
  hipLaunchKernelGGL((gemm_nt<1,false,false>), dim3(256/64, (BZ*PP)/64), dim3(256), 0, stream,
                     hidG, h2w, h2b, out, (__hip_bfloat16*)nullptr,
                     BZ*PP, 256, DM);
  hipLaunchKernelGGL(adj_kernel, dim3(BZ, PP), dim3(64), 0, stream, lastsG, adj);
}

// Round 13
// 3758.519 us; speedup vs baseline: 4.8533x; 4.8533x over previous
//
#include <hip/hip_runtime.h>
#include <hip/hip_bf16.h>
#include <math.h>

#define DEV __device__ __forceinline__
typedef unsigned int u32;
typedef unsigned short u16;

constexpr int NNODES = 16384;
constexpr int NEDGE  = 262144;
constexpr int NEL    = NEDGE + NNODES;
constexpr int FIN    = 256;
constexpr int C1     = 384;
constexpr int DM     = 192;
constexpr int BZ     = 128;
constexpr int NPG_   = 128;
constexpr int LL     = 4;
constexpr int PP     = 32;
constexpr int SM     = 33;
constexpr int DFF_   = 512;

// packed-weight layout (uint4 units, [K/8][N]) per layer
constexpr int PL4     = 52224;
constexpr int OFF4_QKV = 0;        // [24][576]
constexpr int OFF4_SAO = 13824;    // [24][192]
constexpr int OFF4_CAQ = 18432;
constexpr int OFF4_CAO = 23040;
constexpr int OFF4_FF1 = 27648;    // [24][512]
constexpr int OFF4_FF2 = 39936;    // [64][192]

// ---- workspace layout (float units) ----
constexpr size_t O_KVK = 0;                       // CA K bf16 [l][node][192] (overlaps dead XP1)
constexpr size_t O_VT  = 6291456;                 // CA V^T bf16 [l][dim][node] (overlaps dead H)
constexpr size_t O_XP1 = 0;
constexpr size_t O_H   = 6291456;
constexpr size_t O_XP2 = 12582912;                // also hidG post-decode
constexpr size_t O_MEM = 15728640;
constexpr size_t O_WP  = 20545536;                // packed weights
constexpr size_t O_PE  = 21424128;
constexpr size_t O_AL1S= O_PE + 6336;
constexpr size_t O_AL1D= O_AL1S + 65536;
constexpr size_t O_AL2S= O_AL1D + 65536;
constexpr size_t O_AL2D= O_AL2S + 16384;
constexpr size_t O_CNT = O_AL2D + 16384;
constexpr size_t O_BASE= O_CNT + 16384;
constexpr size_t O_FILL= O_BASE + 16384;
constexpr size_t O_CSRC= O_FILL + 16384;
constexpr size_t O_LASTS=O_CSRC + 278528;         // 4096*192 fp32

DEV float gelu_f(float v) { return 0.5f*v*(1.0f + erff(v*0.7071067811865475f)); }
DEV float bflo(u32 w) { return __uint_as_float(w << 16); }
DEV float bfhi(u32 w) { return __uint_as_float(w & 0xffff0000u); }
DEV float bfu(u16 u)  { return __uint_as_float(((u32)u) << 16); }
DEV u16 bf16u(float a) {
  __hip_bfloat16 h = __float2bfloat16(a);
  return *reinterpret_cast<u16*>(&h);
}
DEV u32 pk2(float a, float b) {
  return (u32)bf16u(a) | ((u32)bf16u(b) << 16);
}
DEV void fma8(float& a, uint4 w, float4 xa, float4 xb) {
  a = fmaf(bflo(w.x), xa.x, a); a = fmaf(bfhi(w.x), xa.y, a);
  a = fmaf(bflo(w.y), xa.z, a); a = fmaf(bfhi(w.y), xa.w, a);
  a = fmaf(bflo(w.z), xb.x, a); a = fmaf(bfhi(w.z), xb.y, a);
  a = fmaf(bflo(w.w), xb.z, a); a = fmaf(bfhi(w.w), xb.w, a);
}
template<int NU4, int STRIDE>
DEV float dotcol(const uint4* __restrict__ col, const float* __restrict__ xv) {
  const float4* x4 = (const float4*)xv;
  float a0 = 0, a1 = 0, a2 = 0, a3 = 0;
  #pragma unroll
  for (int q = 0; q < NU4; ++q) {
    uint4 w = col[(size_t)q*STRIDE];
    if ((q & 3) == 0) fma8(a0, w, x4[2*q], x4[2*q+1]);
    else if ((q & 3) == 1) fma8(a1, w, x4[2*q], x4[2*q+1]);
    else if ((q & 3) == 2) fma8(a2, w, x4[2*q], x4[2*q+1]);
    else fma8(a3, w, x4[2*q], x4[2*q+1]);
  }
  return (a0+a1)+(a2+a3);
}
// small prefetch buffer (12 VGPRs)
template<int N> struct WB { uint4 w[N]; };
template<int N, int STRIDE>
DEV void wissue(WB<N>& r, const uint4* __restrict__ col) {
  #pragma unroll
  for (int q = 0; q < N; ++q) r.w[q] = col[(size_t)q*STRIDE];
}
template<int N>
DEV float wuse(const WB<N>& r, const float* __restrict__ xv) {
  const float4* x4 = (const float4*)xv;
  float a0 = 0, a1 = 0, a2 = 0, a3 = 0;
  #pragma unroll
  for (int q = 0; q < N; ++q) {
    float4 xa = x4[2*q], xb = x4[2*q+1];
    if ((q & 3) == 0) fma8(a0, r.w[q], xa, xb);
    else if ((q & 3) == 1) fma8(a1, r.w[q], xa, xb);
    else if ((q & 3) == 2) fma8(a2, r.w[q], xa, xb);
    else fma8(a3, r.w[q], xa, xb);
  }
  return (a0+a1)+(a2+a3);
}

// ---------------- misc ----------------
__global__ void zero_kernel(float* adj, int* cnt, int* fill) {
  int i = blockIdx.x*256 + threadIdx.x;
  if (i < BZ*SM*SM) adj[i] = 0.f;
  if (i < NNODES) { cnt[i] = 0; fill[i] = 0; }
}

__global__ void pe_kernel(float* pe) {
  int idx = blockIdx.x*256 + threadIdx.x;
  if (idx >= SM*DM) return;
  int p = idx / DM, d = idx % DM;
  int i2 = d >> 1;
  float div = __expf((float)(2*i2) * (-9.210340371976184f / (float)DM));
  float a = (float)p * div;
  pe[idx] = (d & 1) ? cosf(a) : sinf(a);
}

__global__ void pack_kernel(const float* __restrict__ W, uint4* __restrict__ P, int N, int K) {
  int idx = blockIdx.x*256 + threadIdx.x;
  if (idx >= N*(K>>3)) return;
  int o = idx % N, kq = idx / N;
  const float* r = W + (size_t)o*K + 8*kq;
  uint4 u;
  u.x = pk2(r[0], r[1]); u.y = pk2(r[2], r[3]);
  u.z = pk2(r[4], r[5]); u.w = pk2(r[6], r[7]);
  P[idx] = u;
}

// ---------------- generic fp32 GEMM: C[M,N] = A[M,K] @ W[N,K]^T (+bias, opt gelu) --------
template<int BMODE, bool BF16OUT, bool GELU = false>
__global__ __launch_bounds__(256) void gemm_nt(const float* __restrict__ A,
    const float* __restrict__ W, const float* __restrict__ bias,
    float* __restrict__ Cf, __hip_bfloat16* __restrict__ Cb, int M, int N, int K)
{
  __shared__ float As[16][68];
  __shared__ float Ws[16][68];
  const int bm = blockIdx.y*64, bn = blockIdx.x*64;
  const int t = threadIdx.x, tx = t & 15, ty = t >> 4;
  float acc[4][4] = {};
  for (int k0 = 0; k0 < K; k0 += 16) {
    #pragma unroll
    for (int i = 0; i < 4; ++i) {
      int idx = t + i*256, kk = idx & 15, m = idx >> 4;
      As[kk][m] = A[(size_t)(bm+m)*K + k0+kk];
      Ws[kk][m] = W[(size_t)(bn+m)*K + k0+kk];
    }
    __syncthreads();
    #pragma unroll
    for (int kk = 0; kk < 16; ++kk) {
      const float4 a4 = *(const float4*)&As[kk][ty*4];
      const float4 b4 = *(const float4*)&Ws[kk][tx*4];
      const float av[4] = {a4.x,a4.y,a4.z,a4.w};
      const float bv[4] = {b4.x,b4.y,b4.z,b4.w};
      #pragma unroll
      for (int i = 0; i < 4; ++i)
        #pragma unroll
        for (int j = 0; j < 4; ++j)
          acc[i][j] = fmaf(av[i], bv[j], acc[i][j]);
    }
    __syncthreads();
  }
  #pragma unroll
  for (int i = 0; i < 4; ++i) {
    const int m = bm + ty*4 + i;
    #pragma unroll
    for (int j = 0; j < 4; ++j) {
      const int n = bn + tx*4 + j;
      float v = acc[i][j];
      if (BMODE == 1) v += bias[n];
      if (BMODE == 2) v += bias[m];
      if (GELU) v = gelu_f(v);
      if (BF16OUT) Cb[(size_t)m*N + n] = __float2bfloat16(v);
      else         Cf[(size_t)m*N + n] = v;
    }
  }
}

// ---------------- GAT helpers ----------------
template<int HEADS, int CH>
__global__ void al_kernel(const float* __restrict__ xp, const float* __restrict__ asrc,
                          const float* __restrict__ adst, float* als, float* ald) {
  int idx = blockIdx.x*256 + threadIdx.x;
  if (idx >= NNODES*HEADS) return;
  int n = idx / HEADS, h = idx % HEADS;
  const float* row = xp + (size_t)n*(HEADS*CH) + h*CH;
  float s = 0, d = 0;
  for (int c = 0; c < CH; ++c) { float v = row[c]; s = fmaf(v, asrc[h*CH+c], s); d = fmaf(v, adst[h*CH+c], d); }
  als[idx] = s; ald[idx] = d;
}

__global__ void count_kernel(const int* __restrict__ dst, int* cnt) {
  int e = blockIdx.x*256 + threadIdx.x;
  if (e < NEDGE) atomicAdd(&cnt[dst[e]], 1);
}

__global__ __launch_bounds__(1024) void scan_kernel(const int* __restrict__ cnt, int* base) {
  __shared__ int tot[1024];
  int t = threadIdx.x;
  int local[16]; int s = 0;
  #pragma unroll
  for (int i = 0; i < 16; ++i) { int v = cnt[t*16+i] + 1; local[i] = s; s += v; }
  tot[t] = s; __syncthreads();
  if (t == 0) { int r = 0; for (int i = 0; i < 1024; ++i) { int v = tot[i]; tot[i] = r; r += v; } }
  __syncthreads();
  int off = tot[t];
  #pragma unroll
  for (int i = 0; i < 16; ++i) base[t*16+i] = off + local[i];
}

__global__ void scatter_kernel(const int* __restrict__ src, const int* __restrict__ dst,
                               const int* __restrict__ base, int* fill, int* csrc) {
  int e = blockIdx.x*256 + threadIdx.x;
  if (e < NEDGE) {
    int d = dst[e];
    int p = atomicAdd(&fill[d], 1);
    csrc[base[d] + p] = src[e];
  } else if (e < NEL) {
    int n = e - NEDGE;
    int p = atomicAdd(&fill[n], 1);
    csrc[base[n] + p] = n;
  }
}

template<int HEADS, int CH, bool ELU>
__global__ __launch_bounds__(128) void agg_kernel(const float* __restrict__ xp,
    const float* __restrict__ als, const float* __restrict__ ald,
    const int* __restrict__ cnt, const int* __restrict__ base, const int* __restrict__ csrc,
    const float* __restrict__ bias, float* __restrict__ out)
{
  constexpr int CO = HEADS*CH;
  constexpr int MAXD = 128;
  int n = blockIdx.x, t = threadIdx.x;
  int deg = cnt[n] + 1, st = base[n];
  if (deg > MAXD) deg = MAXD;
  __shared__ int   srcs[MAXD];
  __shared__ float ex[MAXD][HEADS];
  __shared__ float den[HEADS];
  for (int j = t; j < deg; j += 128) srcs[j] = csrc[st + j];
  __syncthreads();
  for (int idx = t; idx < deg*HEADS; idx += 128) {
    int j = idx / HEADS, h = idx % HEADS;
    float e = als[srcs[j]*HEADS + h] + ald[n*HEADS + h];
    ex[j][h] = (e > 0.f) ? e : 0.2f*e;
  }
  __syncthreads();
  if (t < HEADS) {
    float m = -1e30f;
    for (int j = 0; j < deg; ++j) m = fmaxf(m, ex[j][t]);
    float s = 0;
    for (int j = 0; j < deg; ++j) { float v = __expf(ex[j][t]-m); ex[j][t] = v; s += v; }
    den[t] = 1.0f/(s + 1e-16f);
  }
  __syncthreads();
  for (int c = t; c < CO; c += 128) {
    int h = c / CH;
    float acc = 0;
    for (int j = 0; j < deg; ++j) acc = fmaf(ex[j][h], xp[(size_t)srcs[j]*CO + c], acc);
    float v = acc*den[h] + bias[c];
    if (ELU) v = (v > 0.f) ? v : (__expf(v) - 1.0f);
    out[(size_t)n*CO + c] = v;
  }
}

// ---------------- post-decode head kernels ----------------
__global__ void adj_kernel(const float* __restrict__ lastsG, float* __restrict__ adj) {
  int b = blockIdx.x, i = blockIdx.y, jj = threadIdx.x;
  if (jj > i) return;
  const float* li = lastsG + ((size_t)b*PP + i)*DM;
  const float* lj = lastsG + ((size_t)b*PP + jj)*DM;
  float a = 0.f;
  for (int d = 0; d < DM; ++d) a = fmaf(lj[d], li[d], a);
  if (jj == 0) {
    adj[((size_t)b*SM + i)*SM + 32] = a;
    adj[((size_t)b*SM + 32)*SM + i] = a;
  } else {
    adj[((size_t)b*SM + jj-1)*SM + i] = a;
    adj[((size_t)b*SM + i)*SM + jj-1] = a;
  }
}

// ---------------- decode (R10 structure; head extracted) ----------------
__global__ __launch_bounds__(1024) void decode_kernel(
    const float* __restrict__ mem, const u16* __restrict__ kvk, const u16* __restrict__ vT,
    const uint4* __restrict__ wp, const float* __restrict__ pe,
    const int* __restrict__ tgt_idx,
    const float* __restrict__ saqkvb, const float* __restrict__ saoutb,
    const float* __restrict__ caqkvb, const float* __restrict__ caoutb,
    const float* __restrict__ ff1b, const float* __restrict__ ff2b,
    const float* __restrict__ lng, const float* __restrict__ lnb,
    float* __restrict__ lastsG)
{
  const int b = blockIdx.x, t = threadIdx.x;
  const int wv = t >> 6, lane = t & 63;
  __shared__ u16   ksa16[4*33*194];      // SA K cache, row stride 194 u16 (97 u32)
  __shared__ u16   vsa16[4*33*194];      // SA V cache in LDS
  __shared__ __align__(16) float x[DM];
  __shared__ __align__(16) float qkv[DM];   // SA q, then CA q
  __shared__ __align__(16) float attno[DM];
  __shared__ __align__(16) float hid[DFF_];
  __shared__ float prob[33*9 + 7];
  __shared__ float cprob[128*9 + 2];
  __shared__ __align__(16) float psA[1152];
  __shared__ float painv[8], cainv[8], red[16];
  const float scl = 0.2041241452319315f; // 1/sqrt(24)
  const float* tgt0 = mem + ((size_t)b*NPG_ + tgt_idx[b])*DM;
  const uint4* kvk4 = (const uint4*)kvk;

  // static per-thread mappings
  const int qks = t / 576, qcol = t - qks*576;              // QKV split-K2
  const int k4s = t >> 9,  o512 = t & 511;                  // FF1
  const int ks4 = (t < 768) ? t/192 : 0;                    // 768-unit phases
  const int o192 = t - ((t < 768) ? (t/192)*192 : 0);
  const int caj = t >> 3, cah = t & 7;                      // CA QK (key,head)

  WB<3> rCAK;   // the ONLY prefetch buffer (12 VGPRs)

  auto ln_ps4 = [&](const float* g, const float* be) {
    float v = 0.f;
    if (t < DM) v = x[t] + ((psA[t]+psA[192+t]) + (psA[384+t]+psA[576+t]));
    float s = v, q = v*v;
    #pragma unroll
    for (int o = 32; o; o >>= 1) { s += __shfl_down(s, o, 64); q += __shfl_down(q, o, 64); }
    if (lane == 0 && wv < 3) { red[wv] = s; red[8+wv] = q; }
    __syncthreads();
    float S = red[0]+red[1]+red[2];
    float Q = red[8]+red[9]+red[10];
    float mu = S*(1.f/DM), var = Q*(1.f/DM) - mu*mu;
    float rstd = rsqrtf(var + 1e-5f);
    if (t < DM) x[t] = (v-mu)*rstd*g[t] + be[t];
    __syncthreads();
  };

  // prologue
  if (t < DM) x[t] = tgt0[t] + pe[t];
  __syncthreads();

  for (int i = 0; i < PP; ++i) {
    for (int l = 0; l < LL; ++l) {
      const uint4* WL = wp + (size_t)l*PL4;
      // P1: SA qkv GEMV (1152 units) + CA-K prefetch into registers
      {
        psA[t] = (qks ? 0.f : saqkvb[l*576 + qcol]) + dotcol<12,576>(WL + OFF4_QKV + qks*12*576 + qcol, x + 96*qks);
        if (t < 128)
          psA[1024 + t] = dotcol<12,576>(WL + OFF4_QKV + 12*576 + 448 + t, x + 96);
      }
      wissue<3,1>(rCAK, kvk4 + ((size_t)l*NNODES + b*NPG_ + caj)*24 + cah*3);
      __syncthreads();
      // P2: route qkv -> q(LDS f32) / K-cache(LDS) / V-cache(LDS)
      if (t < 576) {
        float a = psA[t] + psA[576 + t];
        if (t < 192)      qkv[t] = a;
        else if (t < 384) ksa16[(l*33 + i)*194 + (t-192)] = bf16u(a);
        else              vsa16[(l*33 + i)*194 + (t-384)] = bf16u(a);
      }
      __syncthreads();
      // P3: SA QK^T + softmax (waves 0-7 = heads, lane = key)
      if (wv < 8) {
        float s = -1e30f;
        if (lane <= i) {
          const u32* kr = (const u32*)ksa16 + ((size_t)l*33 + lane)*97 + wv*12;
          float a0 = 0, a1 = 0;
          #pragma unroll
          for (int c = 0; c < 12; c += 2) {
            u32 w0 = kr[c], w1 = kr[c+1];
            a0 = fmaf(bflo(w0), qkv[wv*24 + 2*c],   a0);
            a0 = fmaf(bfhi(w0), qkv[wv*24 + 2*c+1], a0);
            a1 = fmaf(bflo(w1), qkv[wv*24 + 2*c+2], a1);
            a1 = fmaf(bfhi(w1), qkv[wv*24 + 2*c+3], a1);
          }
          s = (a0+a1) * scl;
        }
        float m = s;
        #pragma unroll
        for (int o2 = 32; o2; o2 >>= 1) m = fmaxf(m, __shfl_xor(m, o2, 64));
        float e = (lane <= i) ? __expf(s - m) : 0.f;
        float sm = e;
        #pragma unroll
        for (int o2 = 32; o2; o2 >>= 1) sm += __shfl_xor(sm, o2, 64);
        if (lane <= i) prob[lane*9 + wv] = e;
        if (lane == 0) painv[wv] = 1.0f / sm;
      }
      __syncthreads();
      // P4: SA PV from LDS V cache (thread = dim)
      if (t < DM) {
        int hh = t / 24;
        const u16* vr = vsa16 + (size_t)l*33*194 + t;
        float a0 = 0, a1 = 0;
        for (int j = 0; j + 1 <= i; j += 2) {
          a0 = fmaf(prob[j*9 + hh],     bfu(vr[(size_t)j*194]),     a0);
          a1 = fmaf(prob[(j+1)*9 + hh], bfu(vr[(size_t)(j+1)*194]), a1);
        }
        if (!(i & 1)) a0 = fmaf(prob[i*9 + hh], bfu(vr[(size_t)i*194]), a0);
        attno[t] = (a0 + a1) * painv[hh];
      }
      __syncthreads();
      // P5: SA out (768 units)
      if (t < 768)
        psA[t] = (ks4 ? 0.f : saoutb[l*DM + o192]) + dotcol<6,192>(WL + OFF4_SAO + ks4*6*192 + o192, attno + 48*ks4);
      __syncthreads();
      ln_ps4(lng + (l*3+0)*DM, lnb + (l*3+0)*DM);
      // P8: CA q (768 units)
      if (t < 768)
        psA[t] = (ks4 ? 0.f : caqkvb[l*3*DM + o192]) + dotcol<6,192>(WL + OFF4_CAQ + ks4*6*192 + o192, x + 48*ks4);
      __syncthreads();
      // P9: CA QK^T with prefetched K; fold q-combine (per-thread from psA)
      {
        float4 qv4[6];
        const int cbase = cah*24;
        #pragma unroll
        for (int o2 = 0; o2 < 6; ++o2) {
          float4 v;
          int c0 = cbase + 4*o2;
          v.x = (psA[c0+0]+psA[192+c0+0]) + (psA[384+c0+0]+psA[576+c0+0]);
          v.y = (psA[c0+1]+psA[192+c0+1]) + (psA[384+c0+1]+psA[576+c0+1]);
          v.z = (psA[c0+2]+psA[192+c0+2]) + (psA[384+c0+2]+psA[576+c0+2]);
          v.w = (psA[c0+3]+psA[192+c0+3]) + (psA[384+c0+3]+psA[576+c0+3]);
          qv4[o2] = v;
        }
        cprob[caj*9 + cah] = scl * wuse<3>(rCAK, (const float*)qv4);
      }
      __syncthreads();
      // P10: CA softmax (waves 0-7 = heads)
      if (wv < 8) {
        float s0 = cprob[lane*9 + wv], s1 = cprob[(lane+64)*9 + wv];
        float m = fmaxf(s0, s1);
        #pragma unroll
        for (int o2 = 32; o2; o2 >>= 1) m = fmaxf(m, __shfl_xor(m, o2, 64));
        float e0 = __expf(s0-m), e1 = __expf(s1-m);
        float sm = e0+e1;
        #pragma unroll
        for (int o2 = 32; o2; o2 >>= 1) sm += __shfl_xor(sm, o2, 64);
        cprob[lane*9 + wv] = e0; cprob[(lane+64)*9 + wv] = e1;
        if (lane == 0) cainv[wv] = 1.0f / sm;
      }
      __syncthreads();
      // P11: CA PV (thread=dim, all 128 keys from contiguous 256B vT row, fold cainv)
      if (t < DM) {
        int hh = t / 24;
        const uint4* v4 = (const uint4*)(vT + ((size_t)l*DM + t)*NNODES + b*NPG_);
        float a0 = 0, a1 = 0;
        #pragma unroll
        for (int q = 0; q < 16; ++q) {
          uint4 w = v4[q];
          int j0 = q*8;
          a0 = fmaf(cprob[(j0+0)*9 + hh], bflo(w.x), a0);
          a1 = fmaf(cprob[(j0+1)*9 + hh], bfhi(w.x), a1);
          a0 = fmaf(cprob[(j0+2)*9 + hh], bflo(w.y), a0);
          a1 = fmaf(cprob[(j0+3)*9 + hh], bfhi(w.y), a1);
          a0 = fmaf(cprob[(j0+4)*9 + hh], bflo(w.z), a0);
          a1 = fmaf(cprob[(j0+5)*9 + hh], bfhi(w.z), a1);
          a0 = fmaf(cprob[(j0+6)*9 + hh], bflo(w.w), a0);
          a1 = fmaf(cprob[(j0+7)*9 + hh], bfhi(w.w), a1);
        }
        attno[t] = (a0 + a1) * cainv[hh];
      }
      __syncthreads();
      // P12: CA out (768 units)
      if (t < 768)
        psA[t] = (ks4 ? 0.f : caoutb[l*DM + o192]) + dotcol<6,192>(WL + OFF4_CAO + ks4*6*192 + o192, attno + 48*ks4);
      __syncthreads();
      ln_ps4(lng + (l*3+1)*DM, lnb + (l*3+1)*DM);
      // P15: FF1 (1024 units)
      psA[t] = (k4s ? 0.f : ff1b[l*DFF_ + o512]) + dotcol<12,512>(WL + OFF4_FF1 + k4s*12*512 + o512, x + 96*k4s);
      __syncthreads();
      // P16: gelu
      if (t < DFF_) hid[t] = gelu_f(psA[t] + psA[512+t]);
      __syncthreads();
      // P17: FF2 (768 units)
      if (t < 768)
        psA[t] = (ks4 ? 0.f : ff2b[l*DM + o192]) + dotcol<16,192>(WL + OFF4_FF2 + ks4*16*192 + o192, hid + 128*ks4);
      __syncthreads();
      ln_ps4(lng + (l*3+2)*DM, lnb + (l*3+2)*DM);
    }
    // step-final: store lasts to global; advance x for next step
    if (t < DM) {
      float xv = x[t];
      lastsG[((size_t)b*PP + i)*DM + t] = xv;
      if (i + 1 < PP) x[t] = xv + pe[(i+1)*DM + t];
    }
    __syncthreads();
  }
}

// ---------------- launch ----------------
extern "C" void kernel_launch(void* const* d_in, const int* in_sizes, int n_in,
                              void* d_out, int out_size, void* d_ws, size_t ws_size,
                              hipStream_t stream) {
  (void)in_sizes; (void)n_in; (void)out_size; (void)ws_size;
  const float* x_in    = (const float*)d_in[0];
  const int*   ei      = (const int*)d_in[1];
  const int*   tgt_idx = (const int*)d_in[2];
  const float* gat1_w  = (const float*)d_in[5];
  const float* g1as    = (const float*)d_in[6];
  const float* g1ad    = (const float*)d_in[7];
  const float* g1b     = (const float*)d_in[8];
  const float* gat2_w  = (const float*)d_in[9];
  const float* g2as    = (const float*)d_in[10];
  const float* g2ad    = (const float*)d_in[11];
  const float* g2b     = (const float*)d_in[12];
  const float* saqkvw  = (const float*)d_in[13];
  const float* saqkvb  = (const float*)d_in[14];
  const float* saoutw  = (const float*)d_in[15];
  const float* saoutb  = (const float*)d_in[16];
  const float* caqkvw  = (const float*)d_in[17];
  const float* caqkvb  = (const float*)d_in[18];
  const float* caoutw  = (const float*)d_in[19];
  const float* caoutb  = (const float*)d_in[20];
  const float* ff1w    = (const float*)d_in[21];
  const float* ff1b    = (const float*)d_in[22];
  const float* ff2w    = (const float*)d_in[23];
  const float* ff2b    = (const float*)d_in[24];
  const float* lng     = (const float*)d_in[25];
  const float* lnb     = (const float*)d_in[26];
  const float* h1w     = (const float*)d_in[27];
  const float* h1b     = (const float*)d_in[28];
  const float* h2w     = (const float*)d_in[29];
  const float* h2b     = (const float*)d_in[30];

  float* ws  = (float*)d_ws;
  float* out = (float*)d_out;
  float* adj = out + (size_t)BZ*PP*256;

  const int* src = ei;
  const int* dst = ei + NEDGE;

  int* cnt  = (int*)(ws + O_CNT);
  int* base = (int*)(ws + O_BASE);
  int* fill = (int*)(ws + O_FILL);
  int* csrc = (int*)(ws + O_CSRC);
  float* lastsG = ws + O_LASTS;
  float* hidG   = ws + O_XP2;     // dead post-decode

  hipLaunchKernelGGL(zero_kernel, dim3(545), dim3(256), 0, stream, adj, cnt, fill);

  // ---- GAT1 ----
  hipLaunchKernelGGL((gemm_nt<0,false>), dim3(C1/64, NNODES/64), dim3(256), 0, stream,
                     x_in, gat1_w, (const float*)nullptr, ws + O_XP1, (__hip_bfloat16*)nullptr,
                     NNODES, C1, FIN);
  hipLaunchKernelGGL((al_kernel<4,96>), dim3(NNODES*4/256), dim3(256), 0, stream,
                     ws+O_XP1, g1as, g1ad, ws+O_AL1S, ws+O_AL1D);
  hipLaunchKernelGGL(count_kernel, dim3(NEDGE/256), dim3(256), 0, stream, dst, cnt);
  hipLaunchKernelGGL(scan_kernel, dim3(1), dim3(1024), 0, stream, cnt, base);
  hipLaunchKernelGGL(scatter_kernel, dim3(NEL/256), dim3(256), 0, stream, src, dst, base, fill, csrc);
  hipLaunchKernelGGL((agg_kernel<4,96,true>), dim3(NNODES), dim3(128), 0, stream,
                     ws+O_XP1, ws+O_AL1S, ws+O_AL1D, cnt, base, csrc, g1b, ws+O_H);

  // ---- GAT2 ----
  hipLaunchKernelGGL((gemm_nt<0,false>), dim3(DM/64, NNODES/64), dim3(256), 0, stream,
                     ws+O_H, gat2_w, (const float*)nullptr, ws+O_XP2, (__hip_bfloat16*)nullptr,
                     NNODES, DM, C1);
  hipLaunchKernelGGL((al_kernel<1,192>), dim3(NNODES/256), dim3(256), 0, stream,
                     ws+O_XP2, g2as, g2ad, ws+O_AL2S, ws+O_AL2D);
  hipLaunchKernelGGL((agg_kernel<1,192,false>), dim3(NNODES), dim3(128), 0, stream,
                     ws+O_XP2, ws+O_AL2S, ws+O_AL2D, cnt, base, csrc, g2b, ws+O_MEM);

  // ---- pack decode weights to bf16 [K/8][N] uint4 ----
  uint4* wp = (uint4*)(ws + O_WP);
  auto PK = [&](const float* Wsrc, int off_u4, int N, int K) {
    hipLaunchKernelGGL(pack_kernel, dim3((N*(K/8)+255)/256), dim3(256), 0, stream,
                       Wsrc, wp + off_u4, N, K);
  };
  for (int l = 0; l < LL; ++l) {
    PK(saqkvw + (size_t)l*110592, l*PL4 + OFF4_QKV, 576, 192);
    PK(saoutw + (size_t)l*36864,  l*PL4 + OFF4_SAO, 192, 192);
    PK(caqkvw + (size_t)l*110592, l*PL4 + OFF4_CAQ, 192, 192);  // first 192 rows = Wq
    PK(caoutw + (size_t)l*36864,  l*PL4 + OFF4_CAO, 192, 192);
    PK(ff1w   + (size_t)l*98304,  l*PL4 + OFF4_FF1, 512, 192);
    PK(ff2w   + (size_t)l*98304,  l*PL4 + OFF4_FF2, 192, 512);
  }

  hipLaunchKernelGGL(pe_kernel, dim3((SM*DM+255)/256), dim3(256), 0, stream, ws+O_PE);

  // ---- CA K (row layout) and V (transposed [dim][node]) hoisted per layer ----
  __hip_bfloat16* kvk = (__hip_bfloat16*)(ws + O_KVK);
  __hip_bfloat16* vT  = (__hip_bfloat16*)(ws + O_VT);
  for (int l = 0; l < LL; ++l) {
    hipLaunchKernelGGL((gemm_nt<1,true>), dim3(DM/64, NNODES/64), dim3(256), 0, stream,
                       ws+O_MEM, caqkvw + (size_t)l*110592 + (size_t)192*192,
                       caqkvb + l*576 + 192, (float*)nullptr,
                       kvk + (size_t)l*NNODES*DM, NNODES, DM, DM);
    hipLaunchKernelGGL((gemm_nt<2,true>), dim3(NNODES/64, DM/64), dim3(256), 0, stream,
                       caqkvw + (size_t)l*110592 + (size_t)2*192*192, ws+O_MEM,
                       caqkvb + l*576 + 384, (float*)nullptr,
                       vT + (size_t)l*DM*NNODES, DM, NNODES, DM);
  }

  hipLaunchKernelGGL(decode_kernel, dim3(BZ), dim3(1024), 0, stream,
                     ws+O_MEM, (const u16*)kvk, (const u16*)vT, wp, ws+O_PE, tgt_idx,
                     saqkvb, saoutb, caqkvb, caoutb, ff1b, ff2b, lng, lnb,
                     lastsG);

  // ---- head (parallel, after decode): feats = gelu(lasts@h1^T)@h2^T ; adj dots ----
  hipLaunchKernelGGL((gemm_nt<1,false,true>), dim3(DM/64, (BZ*PP)/64), dim3(256), 0, stream,
                     lastsG, h1w, h1b, hidG, (__hip_bfloat16*)nullptr,
                     BZ*PP, DM, DM);
  hipLaunchKernelGGL((gemm_nt<1,false,false>), dim3(256/64, (BZ*PP)/64), dim3(256), 0, stream,
                     hidG, h2w, h2b, out, (__hip_bfloat16*)nullptr,
                     BZ*PP, 256, DM);
  hipLaunchKernelGGL(adj_kernel, dim3(BZ, PP), dim3(64), 0, stream, lastsG, adj);
}